// Round 1
// baseline (955.280 us; speedup 1.0000x reference)
//
#include <hip/hip_runtime.h>
#include <math.h>

#define N_NODES 100000
#define N_EDGES 1600000
#define F_IN 64
#define SCAN_B 256
#define NB ((N_NODES + SCAN_B - 1) / SCAN_B)   // 391

__global__ void k_zero(int* __restrict__ p, int n) {
    int i = blockIdx.x * blockDim.x + threadIdx.x;
    if (i < n) p[i] = 0;
}

__global__ void k_deg(const int* __restrict__ row, const int* __restrict__ col,
                      int* __restrict__ deg_out, int* __restrict__ deg_in) {
    int e = blockIdx.x * blockDim.x + threadIdx.x;
    if (e < N_EDGES) {
        atomicAdd(&deg_out[row[e]], 1);
        atomicAdd(&deg_in[col[e]], 1);
    }
}

__global__ void k_inv(const int* __restrict__ deg_out, const int* __restrict__ deg_in,
                      float* __restrict__ inv_out, float* __restrict__ inv_in) {
    int i = blockIdx.x * blockDim.x + threadIdx.x;
    if (i < N_NODES) {
        int dov = deg_out[i];
        int div = deg_in[i];
        inv_out[i] = dov > 0 ? rsqrtf((float)dov) : 0.0f;
        inv_in[i]  = div > 0 ? rsqrtf((float)div) : 0.0f;
    }
}

// per-block exclusive scan of deg_out -> row_ptr (partial), block totals -> blockSums
__global__ void k_scan1(const int* __restrict__ deg, int* __restrict__ row_ptr,
                        int* __restrict__ blockSums) {
    __shared__ int s[SCAN_B];
    int t = threadIdx.x;
    int i = blockIdx.x * SCAN_B + t;
    int v = (i < N_NODES) ? deg[i] : 0;
    s[t] = v;
    __syncthreads();
    for (int off = 1; off < SCAN_B; off <<= 1) {
        int add = (t >= off) ? s[t - off] : 0;
        __syncthreads();
        s[t] += add;
        __syncthreads();
    }
    if (i < N_NODES) row_ptr[i] = s[t] - v;  // exclusive
    if (t == SCAN_B - 1) blockSums[blockIdx.x] = s[t];
}

// serial scan of 391 block sums (tiny)
__global__ void k_scan2(int* __restrict__ blockSums) {
    if (threadIdx.x == 0 && blockIdx.x == 0) {
        int run = 0;
        for (int b = 0; b < NB; b++) {
            int v = blockSums[b];
            blockSums[b] = run;
            run += v;
        }
    }
}

__global__ void k_scan3(int* __restrict__ row_ptr, const int* __restrict__ blockSums,
                        int* __restrict__ cursor) {
    int i = blockIdx.x * blockDim.x + threadIdx.x;
    if (i < N_NODES) {
        int rp = row_ptr[i] + blockSums[i / SCAN_B];
        row_ptr[i] = rp;
        cursor[i] = rp;
        if (i == 0) row_ptr[N_NODES] = N_EDGES;
    }
}

__global__ void k_scatter(const int* __restrict__ row, const int* __restrict__ col,
                          int* __restrict__ cursor, int* __restrict__ csr_col) {
    int e = blockIdx.x * blockDim.x + threadIdx.x;
    if (e < N_EDGES) {
        int slot = atomicAdd(&cursor[row[e]], 1);
        csr_col[slot] = col[e];
    }
}

// Fused: y[r] = inv_out[r] * sum_{c in N(r)} inv_in[c] * relu?(Xin[c,:]); out = y @ W + b
// One wave per row; lane = input-feature index during gather, output index during GEMM.
template <int FOUT, bool RELU_IN, bool LSM>
__global__ __launch_bounds__(256) void k_layer(
    const float* __restrict__ Xin, const float* __restrict__ W,
    const float* __restrict__ bias, const int* __restrict__ row_ptr,
    const int* __restrict__ csr_col, const float* __restrict__ inv_out,
    const float* __restrict__ inv_in, float* __restrict__ Yout) {
    __shared__ float Wl[F_IN * FOUT];
    __shared__ float accb[4][F_IN];
    int t = threadIdx.x;
    for (int i = t; i < F_IN * FOUT; i += 256) Wl[i] = W[i];
    int wave = t >> 6, lane = t & 63;
    int r = blockIdx.x * 4 + wave;

    float acc = 0.0f;
    int s = row_ptr[r], e = row_ptr[r + 1];
    for (int p = s; p < e; ++p) {
        int c = csr_col[p];                 // wave-uniform -> scalar load
        float wgt = inv_in[c];              // wave-uniform
        float xv = Xin[c * F_IN + lane];    // coalesced 256B row read
        if (RELU_IN) xv = fmaxf(xv, 0.0f);
        acc = fmaf(wgt, xv, acc);
    }
    acc *= inv_out[r];
    accb[wave][lane] = acc;
    __syncthreads();   // also orders the Wl staging before the FMA loop

    int j = (lane < FOUT) ? lane : 0;       // clamp to keep LDS index in bounds
    float o = (lane < FOUT) ? bias[lane] : 0.0f;
#pragma unroll
    for (int k = 0; k < F_IN; ++k)
        o = fmaf(accb[wave][k], Wl[k * FOUT + j], o);

    if (!LSM) {
        if (lane < FOUT) Yout[r * FOUT + lane] = o;
    } else {
        float v = (lane < FOUT) ? o : -INFINITY;
        float m = v;
        for (int msk = 32; msk >= 1; msk >>= 1) m = fmaxf(m, __shfl_xor(m, msk));
        float ex = (lane < FOUT) ? expf(o - m) : 0.0f;
        float ssum = ex;
        for (int msk = 32; msk >= 1; msk >>= 1) ssum += __shfl_xor(ssum, msk);
        if (lane < FOUT) Yout[r * FOUT + lane] = o - m - logf(ssum);
    }
}

extern "C" void kernel_launch(void* const* d_in, const int* in_sizes, int n_in,
                              void* d_out, int out_size, void* d_ws, size_t ws_size,
                              hipStream_t stream) {
    const float* x   = (const float*)d_in[0];
    const int*   ei  = (const int*)d_in[1];
    const int*   row = ei;
    const int*   col = ei + N_EDGES;
    const float* W1s = (const float*)d_in[2];
    const float* b1s = (const float*)d_in[3];
    const float* W2s = (const float*)d_in[6];
    const float* b2s = (const float*)d_in[7];
    const float* Wos = (const float*)d_in[10];
    const float* bos = (const float*)d_in[11];

    float* out_h   = (float*)d_out;                       // [N,64]
    float* out_lsm = out_h + (size_t)N_NODES * 64;        // [N,40]

    char* ws = (char*)d_ws;
    size_t off = 0;
    auto alloc = [&](size_t bytes) -> void* {
        void* p = ws + off;
        off += (bytes + 255) / 256 * 256;
        return p;
    };
    int*   deg_out   = (int*)alloc((size_t)N_NODES * 4);
    int*   deg_in    = (int*)alloc((size_t)N_NODES * 4);
    float* inv_out   = (float*)alloc((size_t)N_NODES * 4);
    float* inv_in    = (float*)alloc((size_t)N_NODES * 4);
    int*   row_ptr   = (int*)alloc(((size_t)N_NODES + 1) * 4);
    int*   cursor    = (int*)alloc((size_t)N_NODES * 4);
    int*   blockSums = (int*)alloc((size_t)NB * 4);
    int*   csr_col   = (int*)alloc((size_t)N_EDGES * 4);
    float* x0        = (float*)alloc((size_t)N_NODES * F_IN * 4);

    const int TB = 256;
    int gN = (N_NODES + TB - 1) / TB;        // 391
    int gE = (N_EDGES + TB - 1) / TB;        // 6250

    k_zero<<<gN, TB, 0, stream>>>(deg_out, N_NODES);
    k_zero<<<gN, TB, 0, stream>>>(deg_in, N_NODES);
    k_deg<<<gE, TB, 0, stream>>>(row, col, deg_out, deg_in);
    k_inv<<<gN, TB, 0, stream>>>(deg_out, deg_in, inv_out, inv_in);
    k_scan1<<<NB, SCAN_B, 0, stream>>>(deg_out, row_ptr, blockSums);
    k_scan2<<<1, 64, 0, stream>>>(blockSums);
    k_scan3<<<gN, TB, 0, stream>>>(row_ptr, blockSums, cursor);
    k_scatter<<<gE, TB, 0, stream>>>(row, col, cursor, csr_col);

    int gL = N_NODES / 4;  // 25000 blocks, 4 waves (rows) each
    k_layer<64, false, false><<<gL, 256, 0, stream>>>(x, W1s, b1s, row_ptr, csr_col,
                                                      inv_out, inv_in, x0);
    k_layer<64, true, false><<<gL, 256, 0, stream>>>(x0, W2s, b2s, row_ptr, csr_col,
                                                     inv_out, inv_in, out_h);
    k_layer<40, true, true><<<gL, 256, 0, stream>>>(out_h, Wos, bos, row_ptr, csr_col,
                                                    inv_out, inv_in, out_lsm);
}

// Round 4
// 664.912 us; speedup vs baseline: 1.4367x; 1.4367x over previous
//
#include <hip/hip_runtime.h>
#include <math.h>

#define N_NODES 100000
#define N_EDGES 1600000
#define F_IN 64
#define SCAN_B 256
#define NB ((N_NODES + SCAN_B - 1) / SCAN_B)   // 391

static __device__ __forceinline__ ushort f2b(float f) {
    unsigned u = __float_as_uint(f);
    unsigned r = (u + 0x7fff + ((u >> 16) & 1)) >> 16;   // RNE
    return (ushort)r;
}

__global__ void k_deg(const int* __restrict__ row, const int* __restrict__ col,
                      int* __restrict__ deg_out, int* __restrict__ deg_in) {
    int e = blockIdx.x * blockDim.x + threadIdx.x;
    if (e < N_EDGES) {
        atomicAdd(&deg_out[row[e]], 1);
        atomicAdd(&deg_in[col[e]], 1);
    }
}

__global__ void k_inv(const int* __restrict__ deg_out, const int* __restrict__ deg_in,
                      float* __restrict__ inv_out, float* __restrict__ inv_in) {
    int i = blockIdx.x * blockDim.x + threadIdx.x;
    if (i < N_NODES) {
        int dov = deg_out[i];
        int div = deg_in[i];
        inv_out[i] = dov > 0 ? rsqrtf((float)dov) : 0.0f;
        inv_in[i]  = div > 0 ? rsqrtf((float)div) : 0.0f;
    }
}

// x (f32) -> xb (bf16), 4 elems/thread
__global__ void k_cvt(const float4* __restrict__ x4, ushort4* __restrict__ xb4, int n4) {
    int i = blockIdx.x * blockDim.x + threadIdx.x;
    if (i < n4) {
        float4 v = x4[i];
        ushort4 o;
        o.x = f2b(v.x); o.y = f2b(v.y); o.z = f2b(v.z); o.w = f2b(v.w);
        xb4[i] = o;
    }
}

// per-block exclusive scan of deg_out -> row_ptr (partial), block totals -> blockSums
__global__ void k_scan1(const int* __restrict__ deg, int* __restrict__ row_ptr,
                        int* __restrict__ blockSums) {
    __shared__ int s[SCAN_B];
    int t = threadIdx.x;
    int i = blockIdx.x * SCAN_B + t;
    int v = (i < N_NODES) ? deg[i] : 0;
    s[t] = v;
    __syncthreads();
    for (int off = 1; off < SCAN_B; off <<= 1) {
        int add = (t >= off) ? s[t - off] : 0;
        __syncthreads();
        s[t] += add;
        __syncthreads();
    }
    if (i < N_NODES) row_ptr[i] = s[t] - v;  // exclusive
    if (t == SCAN_B - 1) blockSums[blockIdx.x] = s[t];
}

// parallel scan of 391 block sums in one 512-thread block
__global__ void k_scan2(int* __restrict__ blockSums) {
    __shared__ int s[512];
    int t = threadIdx.x;
    int v = (t < NB) ? blockSums[t] : 0;
    s[t] = v;
    __syncthreads();
    for (int off = 1; off < 512; off <<= 1) {
        int add = (t >= off) ? s[t - off] : 0;
        __syncthreads();
        s[t] += add;
        __syncthreads();
    }
    if (t < NB) blockSums[t] = s[t] - v;  // exclusive
}

__global__ void k_scan3(int* __restrict__ row_ptr, const int* __restrict__ blockSums,
                        int* __restrict__ cursor) {
    int i = blockIdx.x * blockDim.x + threadIdx.x;
    if (i < N_NODES) {
        int rp = row_ptr[i] + blockSums[i / SCAN_B];
        row_ptr[i] = rp;
        cursor[i] = rp;
        if (i == 0) row_ptr[N_NODES] = N_EDGES;
    }
}

// scatter edges into CSR slots; pack {col, weight=inv_in[col]} as int2
__global__ void k_scatter(const int* __restrict__ row, const int* __restrict__ col,
                          int* __restrict__ cursor, const float* __restrict__ inv_in,
                          int2* __restrict__ ew) {
    int e = blockIdx.x * blockDim.x + threadIdx.x;
    if (e < N_EDGES) {
        int c = col[e];
        int slot = atomicAdd(&cursor[row[e]], 1);
        int2 v;
        v.x = c;
        v.y = __float_as_int(inv_in[c]);
        ew[slot] = v;
    }
}

// Fused layer: y[r] = inv_out[r] * sum_e w_e * xb[col_e, :]; o = y @ W + b
// One wave per row; 4x16-lane quarters each walk every 4th edge (4 indep chains).
// lane L: quarter q=L>>4 (edge phase), fl=L&15 -> features fl*4..fl*4+3 (8B bf16 load).
template <int FOUT, bool STORE_F32, bool STORE_BF16, bool LSM>
__global__ __launch_bounds__(256) void k_layer(
    const uint2* __restrict__ xb2,       // [N][16] uint2 = 64 bf16 per row
    const int2* __restrict__ ew,         // [E] {col, w}
    const int* __restrict__ row_ptr,
    const float* __restrict__ inv_out,
    const float* __restrict__ W,         // [64][FOUT]
    const float* __restrict__ bias,      // [FOUT]
    float* __restrict__ Yf32,            // [N][FOUT] or null
    ushort* __restrict__ Ybf) {          // [N][FOUT] bf16(relu(o)) or null
    __shared__ float Wl[F_IN * FOUT];
    __shared__ float accb[4][F_IN];
    int t = threadIdx.x;
    for (int i = t; i < F_IN * FOUT; i += 256) Wl[i] = W[i];
    int wave = t >> 6, lane = t & 63;
    int q = lane >> 4, fl = lane & 15;
    int r = blockIdx.x * 4 + wave;

    float a0 = 0.f, a1 = 0.f, a2 = 0.f, a3 = 0.f;
    int s = row_ptr[r], e = row_ptr[r + 1];
    for (int p = s + q; p < e; p += 4) {
        int2 cw = ew[p];                       // broadcast within quarter
        float w = __int_as_float(cw.y);
        uint2 u = xb2[cw.x * 16 + fl];         // 8B = 4 bf16
        a0 = fmaf(w, __uint_as_float(u.x << 16), a0);
        a1 = fmaf(w, __uint_as_float(u.x & 0xffff0000u), a1);
        a2 = fmaf(w, __uint_as_float(u.y << 16), a2);
        a3 = fmaf(w, __uint_as_float(u.y & 0xffff0000u), a3);
    }
    // combine 4 quarters
    a0 += __shfl_xor(a0, 16); a1 += __shfl_xor(a1, 16);
    a2 += __shfl_xor(a2, 16); a3 += __shfl_xor(a3, 16);
    a0 += __shfl_xor(a0, 32); a1 += __shfl_xor(a1, 32);
    a2 += __shfl_xor(a2, 32); a3 += __shfl_xor(a3, 32);
    float sc = inv_out[r];
    if (q == 0) {
        float4 v; v.x = a0 * sc; v.y = a1 * sc; v.z = a2 * sc; v.w = a3 * sc;
        *(float4*)&accb[wave][fl * 4] = v;
    }
    __syncthreads();   // orders Wl staging + accb writes

    int j = (lane < FOUT) ? lane : 0;
    float o = (lane < FOUT) ? bias[lane] : 0.0f;
#pragma unroll
    for (int k = 0; k < F_IN; ++k)
        o = fmaf(accb[wave][k], Wl[k * FOUT + j], o);

    if (LSM) {
        float v = (lane < FOUT) ? o : -INFINITY;
        float m = v;
        for (int msk = 32; msk >= 1; msk >>= 1) m = fmaxf(m, __shfl_xor(m, msk));
        float ex = (lane < FOUT) ? expf(o - m) : 0.0f;
        float ssum = ex;
        for (int msk = 32; msk >= 1; msk >>= 1) ssum += __shfl_xor(ssum, msk);
        if (lane < FOUT) Yf32[(size_t)r * FOUT + lane] = o - m - logf(ssum);
    } else {
        if (STORE_F32 && lane < FOUT) Yf32[(size_t)r * FOUT + lane] = o;
        if (STORE_BF16 && lane < FOUT) Ybf[(size_t)r * FOUT + lane] = f2b(fmaxf(o, 0.0f));
    }
}

extern "C" void kernel_launch(void* const* d_in, const int* in_sizes, int n_in,
                              void* d_out, int out_size, void* d_ws, size_t ws_size,
                              hipStream_t stream) {
    const float* x   = (const float*)d_in[0];
    const int*   ei  = (const int*)d_in[1];
    const int*   row = ei;
    const int*   col = ei + N_EDGES;
    const float* W1s = (const float*)d_in[2];
    const float* b1s = (const float*)d_in[3];
    const float* W2s = (const float*)d_in[6];
    const float* b2s = (const float*)d_in[7];
    const float* Wos = (const float*)d_in[10];
    const float* bos = (const float*)d_in[11];

    float* out_h   = (float*)d_out;                       // [N,64]
    float* out_lsm = out_h + (size_t)N_NODES * 64;        // [N,40]

    char* ws = (char*)d_ws;
    size_t off = 0;
    auto alloc = [&](size_t bytes) -> void* {
        void* p = ws + off;
        off += (bytes + 255) / 256 * 256;
        return p;
    };
    int*   deg_out   = (int*)alloc((size_t)N_NODES * 4);
    int*   deg_in    = (int*)alloc((size_t)N_NODES * 4);
    float* inv_out   = (float*)alloc((size_t)N_NODES * 4);
    float* inv_in    = (float*)alloc((size_t)N_NODES * 4);
    int*   row_ptr   = (int*)alloc(((size_t)N_NODES + 1) * 4);
    int*   cursor    = (int*)alloc((size_t)N_NODES * 4);
    int*   blockSums = (int*)alloc((size_t)NB * 4);
    int2*  ewbuf     = (int2*)alloc((size_t)N_EDGES * 8);            // 12.8 MB
    ushort* xb       = (ushort*)alloc((size_t)N_NODES * F_IN * 2);   // 12.8 MB (also reused for hb)
    ushort* x0b      = (ushort*)alloc((size_t)N_NODES * F_IN * 2);   // 12.8 MB
    ushort* hb       = xb;   // xb dead after layer 1

    const int TB = 256;
    int gN = (N_NODES + TB - 1) / TB;        // 391
    int gE = (N_EDGES + TB - 1) / TB;        // 6250

    hipMemsetAsync(deg_out, 0, (size_t)N_NODES * 4, stream);
    hipMemsetAsync(deg_in, 0, (size_t)N_NODES * 4, stream);
    k_cvt<<<(N_NODES * F_IN / 4 + TB - 1) / TB, TB, 0, stream>>>(
        (const float4*)x, (ushort4*)xb, N_NODES * F_IN / 4);
    k_deg<<<gE, TB, 0, stream>>>(row, col, deg_out, deg_in);
    k_inv<<<gN, TB, 0, stream>>>(deg_out, deg_in, inv_out, inv_in);
    k_scan1<<<NB, SCAN_B, 0, stream>>>(deg_out, row_ptr, blockSums);
    k_scan2<<<1, 512, 0, stream>>>(blockSums);
    k_scan3<<<gN, TB, 0, stream>>>(row_ptr, blockSums, cursor);
    k_scatter<<<gE, TB, 0, stream>>>(row, col, cursor, inv_in, ewbuf);

    int gL = N_NODES / 4;  // 25000 blocks, 4 waves (rows) each
    // L1: x -> x0b (bf16 relu'd only)
    k_layer<64, false, true, false><<<gL, 256, 0, stream>>>(
        (const uint2*)xb, ewbuf, row_ptr, inv_out, W1s, b1s, nullptr, x0b);
    // L2: x0b -> h (f32 out) + hb (bf16 relu'd)
    k_layer<64, true, true, false><<<gL, 256, 0, stream>>>(
        (const uint2*)x0b, ewbuf, row_ptr, inv_out, W2s, b2s, out_h, hb);
    // L3: hb -> log_softmax (f32 out)
    k_layer<40, true, false, true><<<gL, 256, 0, stream>>>(
        (const uint2*)hb, ewbuf, row_ptr, inv_out, Wos, bos, out_lsm, nullptr);
}

// Round 7
// 569.709 us; speedup vs baseline: 1.6768x; 1.1671x over previous
//
#include <hip/hip_runtime.h>
#include <math.h>

#define N_NODES 100000
#define N_EDGES 1600000
#define F_IN 64
#define SCAN_B 256
#define NB ((N_NODES + SCAN_B - 1) / SCAN_B)   // 391
#define L_BLOCKS 2048
#define L_WAVES (L_BLOCKS * 4)

static __device__ __forceinline__ ushort f2b(float f) {
    unsigned u = __float_as_uint(f);
    unsigned r = (u + 0x7fff + ((u >> 16) & 1)) >> 16;   // RNE
    return (ushort)r;
}
static __device__ __forceinline__ float bl(unsigned u) { return __uint_as_float(u << 16); }
static __device__ __forceinline__ float bh(unsigned u) { return __uint_as_float(u & 0xffff0000u); }
static __device__ __forceinline__ float rdlane(float v, int lane) {
    return __uint_as_float(__builtin_amdgcn_readlane(__float_as_uint(v), lane));
}

// Fused: degree histograms (atomics) + f32->bf16 convert of x.
// N_EDGES == N_NODES*F_IN/4 == 1.6M, so one index space covers both.
__global__ void k_pre(const int* __restrict__ row, const int* __restrict__ col,
                      int* __restrict__ deg_out, int* __restrict__ deg_in,
                      const float4* __restrict__ x4, ushort4* __restrict__ xb4) {
    int i = blockIdx.x * blockDim.x + threadIdx.x;
    if (i < N_EDGES) {
        atomicAdd(&deg_out[row[i]], 1);
        atomicAdd(&deg_in[col[i]], 1);
        float4 v = x4[i];
        ushort4 o;
        o.x = f2b(v.x); o.y = f2b(v.y); o.z = f2b(v.z); o.w = f2b(v.w);
        xb4[i] = o;
    }
}

// per-block exclusive scan of deg_out -> row_ptr (partial), block totals -> blockSums.
// Fused: inv_out/inv_in from degrees.
__global__ void k_scan1(const int* __restrict__ deg_out, const int* __restrict__ deg_in,
                        int* __restrict__ row_ptr, int* __restrict__ blockSums,
                        float* __restrict__ inv_out, float* __restrict__ inv_in) {
    __shared__ int s[SCAN_B];
    int t = threadIdx.x;
    int i = blockIdx.x * SCAN_B + t;
    int v = (i < N_NODES) ? deg_out[i] : 0;
    if (i < N_NODES) {
        int div = deg_in[i];
        inv_out[i] = v > 0 ? rsqrtf((float)v) : 0.0f;
        inv_in[i]  = div > 0 ? rsqrtf((float)div) : 0.0f;
    }
    s[t] = v;
    __syncthreads();
    for (int off = 1; off < SCAN_B; off <<= 1) {
        int add = (t >= off) ? s[t - off] : 0;
        __syncthreads();
        s[t] += add;
        __syncthreads();
    }
    if (i < N_NODES) row_ptr[i] = s[t] - v;  // exclusive
    if (t == SCAN_B - 1) blockSums[blockIdx.x] = s[t];
}

// parallel scan of 391 block sums in one 512-thread block
__global__ void k_scan2(int* __restrict__ blockSums) {
    __shared__ int s[512];
    int t = threadIdx.x;
    int v = (t < NB) ? blockSums[t] : 0;
    s[t] = v;
    __syncthreads();
    for (int off = 1; off < 512; off <<= 1) {
        int add = (t >= off) ? s[t - off] : 0;
        __syncthreads();
        s[t] += add;
        __syncthreads();
    }
    if (t < NB) blockSums[t] = s[t] - v;  // exclusive
}

__global__ void k_scan3(int* __restrict__ row_ptr, const int* __restrict__ blockSums,
                        int* __restrict__ cursor) {
    int i = blockIdx.x * blockDim.x + threadIdx.x;
    if (i < N_NODES) {
        int rp = row_ptr[i] + blockSums[i / SCAN_B];
        row_ptr[i] = rp;
        cursor[i] = rp;
        if (i == 0) row_ptr[N_NODES] = N_EDGES;
    }
}

// scatter edges into CSR slots; pack {col, weight=inv_in[col]} as int2
__global__ void k_scatter(const int* __restrict__ row, const int* __restrict__ col,
                          int* __restrict__ cursor, const float* __restrict__ inv_in,
                          int2* __restrict__ ew) {
    int e = blockIdx.x * blockDim.x + threadIdx.x;
    if (e < N_EDGES) {
        int c = col[e];
        int slot = atomicAdd(&cursor[row[e]], 1);
        int2 v;
        v.x = c;
        v.y = __float_as_int(inv_in[c]);
        ew[slot] = v;
    }
}

// Fused layer: y[r] = inv_out[r] * sum_e w_e * xb[col_e, :]; o = y @ W + b
// One wave per row (grid-stride, ~12 rows/wave). Gather: 8x8-lane groups, each
// group walks every 8th edge with uint4 (16B = 8 bf16) loads -> 8 indep chains.
// GEMM: W held in 64 VGPRs (lane j = column j); y broadcast via v_readlane.
// No LDS anywhere.
template <int FOUT, bool STORE_F32, bool STORE_BF16, bool LSM>
__global__ __launch_bounds__(256, 4) void k_layer(
    const uint4* __restrict__ xb4,       // [N][8] uint4 = 64 bf16 per row
    const int2* __restrict__ ew,         // [E] {col, w}
    const int* __restrict__ row_ptr,
    const float* __restrict__ inv_out,
    const float* __restrict__ W,         // [64][FOUT]
    const float* __restrict__ bias,      // [FOUT]
    float* __restrict__ Yf32,            // [N][FOUT] or null
    ushort* __restrict__ Ybf) {          // [N][FOUT] bf16(relu(o)) or null
    int t = threadIdx.x;
    int lane = t & 63;
    int gw = (blockIdx.x * 256 + t) >> 6;      // global wave id, < L_WAVES
    int g = lane >> 3, fl = lane & 7;

    int j = (lane < FOUT) ? lane : 0;
    float Wreg[64];
#pragma unroll
    for (int k = 0; k < 64; ++k) Wreg[k] = W[k * FOUT + j];
    float bj = bias[j];

    for (int r = gw; r < N_NODES; r += L_WAVES) {
        float a0 = 0.f, a1 = 0.f, a2 = 0.f, a3 = 0.f;
        float a4 = 0.f, a5 = 0.f, a6 = 0.f, a7 = 0.f;
        int s = row_ptr[r], e = row_ptr[r + 1];
        for (int p = s + g; p < e; p += 8) {
            int2 cw = ew[p];                    // 8 lanes/group same addr (64B/wave contiguous)
            float w = __int_as_float(cw.y);
            uint4 u = xb4[cw.x * 8 + fl];       // 16B = 8 bf16
            a0 = fmaf(w, bl(u.x), a0); a1 = fmaf(w, bh(u.x), a1);
            a2 = fmaf(w, bl(u.y), a2); a3 = fmaf(w, bh(u.y), a3);
            a4 = fmaf(w, bl(u.z), a4); a5 = fmaf(w, bh(u.z), a5);
            a6 = fmaf(w, bl(u.w), a6); a7 = fmaf(w, bh(u.w), a7);
        }
        // butterfly combine the 8 groups (after this, lane with fl=f holds y[8f..8f+7])
#pragma unroll
        for (int msk = 8; msk <= 32; msk <<= 1) {
            a0 += __shfl_xor(a0, msk); a1 += __shfl_xor(a1, msk);
            a2 += __shfl_xor(a2, msk); a3 += __shfl_xor(a3, msk);
            a4 += __shfl_xor(a4, msk); a5 += __shfl_xor(a5, msk);
            a6 += __shfl_xor(a6, msk); a7 += __shfl_xor(a7, msk);
        }
        float sc = inv_out[r];

        // GEMM: o_j = sc * sum_k y[k] * W[k][j] + b_j ; y[8m+i] = a_i of lane m
        float acc = 0.f;
#pragma unroll
        for (int m = 0; m < 8; ++m) {
            acc = fmaf(rdlane(a0, m), Wreg[8 * m + 0], acc);
            acc = fmaf(rdlane(a1, m), Wreg[8 * m + 1], acc);
            acc = fmaf(rdlane(a2, m), Wreg[8 * m + 2], acc);
            acc = fmaf(rdlane(a3, m), Wreg[8 * m + 3], acc);
            acc = fmaf(rdlane(a4, m), Wreg[8 * m + 4], acc);
            acc = fmaf(rdlane(a5, m), Wreg[8 * m + 5], acc);
            acc = fmaf(rdlane(a6, m), Wreg[8 * m + 6], acc);
            acc = fmaf(rdlane(a7, m), Wreg[8 * m + 7], acc);
        }
        float o = fmaf(acc, sc, bj);

        if (LSM) {
            float v = (lane < FOUT) ? o : -INFINITY;
            float mx = v;
            for (int msk = 32; msk >= 1; msk >>= 1) mx = fmaxf(mx, __shfl_xor(mx, msk));
            float ex = (lane < FOUT) ? expf(o - mx) : 0.0f;
            float ssum = ex;
            for (int msk = 32; msk >= 1; msk >>= 1) ssum += __shfl_xor(ssum, msk);
            if (lane < FOUT) Yf32[(size_t)r * FOUT + lane] = o - mx - logf(ssum);
        } else {
            if (STORE_F32 && lane < FOUT) Yf32[(size_t)r * FOUT + lane] = o;
            if (STORE_BF16 && lane < FOUT) Ybf[(size_t)r * FOUT + lane] = f2b(fmaxf(o, 0.0f));
        }
    }
}

extern "C" void kernel_launch(void* const* d_in, const int* in_sizes, int n_in,
                              void* d_out, int out_size, void* d_ws, size_t ws_size,
                              hipStream_t stream) {
    const float* x   = (const float*)d_in[0];
    const int*   ei  = (const int*)d_in[1];
    const int*   row = ei;
    const int*   col = ei + N_EDGES;
    const float* W1s = (const float*)d_in[2];
    const float* b1s = (const float*)d_in[3];
    const float* W2s = (const float*)d_in[6];
    const float* b2s = (const float*)d_in[7];
    const float* Wos = (const float*)d_in[10];
    const float* bos = (const float*)d_in[11];

    float* out_h   = (float*)d_out;                       // [N,64]
    float* out_lsm = out_h + (size_t)N_NODES * 64;        // [N,40]

    char* ws = (char*)d_ws;
    size_t off = 0;
    auto alloc = [&](size_t bytes) -> void* {
        void* p = ws + off;
        off += (bytes + 255) / 256 * 256;
        return p;
    };
    int*   degs      = (int*)alloc((size_t)2 * N_NODES * 4);   // deg_out | deg_in contiguous
    int*   deg_out   = degs;
    int*   deg_in    = degs + N_NODES;
    float* inv_out   = (float*)alloc((size_t)N_NODES * 4);
    float* inv_in    = (float*)alloc((size_t)N_NODES * 4);
    int*   row_ptr   = (int*)alloc(((size_t)N_NODES + 1) * 4);
    int*   cursor    = (int*)alloc((size_t)N_NODES * 4);
    int*   blockSums = (int*)alloc((size_t)NB * 4);
    int2*  ewbuf     = (int2*)alloc((size_t)N_EDGES * 8);            // 12.8 MB
    ushort* xb       = (ushort*)alloc((size_t)N_NODES * F_IN * 2);   // 12.8 MB (reused for hb)
    ushort* x0b      = (ushort*)alloc((size_t)N_NODES * F_IN * 2);   // 12.8 MB
    ushort* hb       = xb;   // xb dead after layer 1

    const int TB = 256;
    int gN = (N_NODES + TB - 1) / TB;        // 391
    int gE = (N_EDGES + TB - 1) / TB;        // 6250

    hipMemsetAsync(degs, 0, (size_t)2 * N_NODES * 4, stream);
    k_pre<<<gE, TB, 0, stream>>>(row, col, deg_out, deg_in, (const float4*)x, (ushort4*)xb);
    k_scan1<<<NB, SCAN_B, 0, stream>>>(deg_out, deg_in, row_ptr, blockSums, inv_out, inv_in);
    k_scan2<<<1, 512, 0, stream>>>(blockSums);
    k_scan3<<<gN, TB, 0, stream>>>(row_ptr, blockSums, cursor);
    k_scatter<<<gE, TB, 0, stream>>>(row, col, cursor, inv_in, ewbuf);

    // L1: x -> x0b (bf16 relu'd only)
    k_layer<64, false, true, false><<<L_BLOCKS, 256, 0, stream>>>(
        (const uint4*)xb, ewbuf, row_ptr, inv_out, W1s, b1s, nullptr, x0b);
    // L2: x0b -> h (f32 out) + hb (bf16 relu'd)
    k_layer<64, true, true, false><<<L_BLOCKS, 256, 0, stream>>>(
        (const uint4*)x0b, ewbuf, row_ptr, inv_out, W2s, b2s, out_h, hb);
    // L3: hb -> log_softmax (f32 out)
    k_layer<40, true, false, true><<<L_BLOCKS, 256, 0, stream>>>(
        (const uint4*)hb, ewbuf, row_ptr, inv_out, Wos, bos, out_lsm, nullptr);
}